// Round 4
// baseline (256.439 us; speedup 1.0000x reference)
//
#include <hip/hip_runtime.h>

#define ITERS 20

// One wave (64 lanes) per 64x64 matrix. Lane (lr=lane>>3, lc=lane&7) owns
// rows {i*8+lr : i=0..7} x cols {lc*8 .. lc*8+7} -> E[8][8] in VGPRs.
// Sinkhorn dual form: B_j = 1/sum_i E_ij*A_i ; A_i = 1/sum_j E_ij*B_j.
// out = E_ij * A_i * B_j.
__global__ __launch_bounds__(256) void sinkhorn_kernel(
    const float* __restrict__ x, float* __restrict__ out) {
    const int wave = threadIdx.x >> 6;            // 0..3
    const int lane = threadIdx.x & 63;
    const size_t mat = (size_t)blockIdx.x * 4 + wave;
    const float* xm = x + mat * 4096;
    float* om = out + mat * 4096;

    const int lr = lane >> 3;   // row group: rows r = i*8 + lr
    const int lc = lane & 7;    // col group: cols c = lc*8 + j

    // Load + exp once. E stays constant across all iterations.
    float E[8][8];
#pragma unroll
    for (int i = 0; i < 8; ++i) {
        const float4 v0 = *(const float4*)(xm + (i * 8 + lr) * 64 + lc * 8);
        const float4 v1 = *(const float4*)(xm + (i * 8 + lr) * 64 + lc * 8 + 4);
        E[i][0] = __expf(v0.x); E[i][1] = __expf(v0.y);
        E[i][2] = __expf(v0.z); E[i][3] = __expf(v0.w);
        E[i][4] = __expf(v1.x); E[i][5] = __expf(v1.y);
        E[i][6] = __expf(v1.z); E[i][7] = __expf(v1.w);
    }

    float A[8], B[8];
#pragma unroll
    for (int i = 0; i < 8; ++i) A[i] = 1.0f;

#pragma unroll 1
    for (int t = 0; t < ITERS; ++t) {
        // ---- column pass: S_j = sum_i E_ij * A_i (over all 64 rows) ----
        float S[8];
#pragma unroll
        for (int j = 0; j < 8; ++j) {
            float s = E[0][j] * A[0];
#pragma unroll
            for (int i = 1; i < 8; ++i) s = fmaf(E[i][j], A[i], s);
            S[j] = s;
        }
        // cross-lane over lr (lane bits 3..5): xor 8,16,32
#pragma unroll
        for (int m = 8; m <= 32; m <<= 1) {
#pragma unroll
            for (int j = 0; j < 8; ++j) S[j] += __shfl_xor(S[j], m, 64);
        }
#pragma unroll
        for (int j = 0; j < 8; ++j) B[j] = __builtin_amdgcn_rcpf(S[j]);

        // ---- row pass: T_i = sum_j E_ij * B_j (over all 64 cols) ----
        float T[8];
#pragma unroll
        for (int i = 0; i < 8; ++i) {
            float s = E[i][0] * B[0];
#pragma unroll
            for (int j = 1; j < 8; ++j) s = fmaf(E[i][j], B[j], s);
            T[i] = s;
        }
        // cross-lane over lc (lane bits 0..2): xor 1,2,4
#pragma unroll
        for (int m = 1; m <= 4; m <<= 1) {
#pragma unroll
            for (int i = 0; i < 8; ++i) T[i] += __shfl_xor(T[i], m, 64);
        }
#pragma unroll
        for (int i = 0; i < 8; ++i) A[i] = __builtin_amdgcn_rcpf(T[i]);
    }

    // ---- epilogue: out = E * A_i * B_j ----
#pragma unroll
    for (int i = 0; i < 8; ++i) {
        const float ai = A[i];
        float4 w0, w1;
        w0.x = E[i][0] * B[0] * ai; w0.y = E[i][1] * B[1] * ai;
        w0.z = E[i][2] * B[2] * ai; w0.w = E[i][3] * B[3] * ai;
        w1.x = E[i][4] * B[4] * ai; w1.y = E[i][5] * B[5] * ai;
        w1.z = E[i][6] * B[6] * ai; w1.w = E[i][7] * B[7] * ai;
        *(float4*)(om + (i * 8 + lr) * 64 + lc * 8) = w0;
        *(float4*)(om + (i * 8 + lr) * 64 + lc * 8 + 4) = w1;
    }
}

extern "C" void kernel_launch(void* const* d_in, const int* in_sizes, int n_in,
                              void* d_out, int out_size, void* d_ws, size_t ws_size,
                              hipStream_t stream) {
    const float* x = (const float*)d_in[0];
    float* out = (float*)d_out;
    // 8192 matrices, 4 per block (one wave each)
    sinkhorn_kernel<<<dim3(2048), dim3(256), 0, stream>>>(x, out);
}